// Round 7
// baseline (246.469 us; speedup 1.0000x reference)
//
#include <hip/hip_runtime.h>
#include <math.h>

// Problem constants (from reference): T=128, B=2048, D=256, ALPHA=0.5, VTH=1.0
#define TT 128
#define BB 2048
#define DDIM 256
#define BD (BB * DDIM)

// GL coefficients c[j] = prod_{i=1..j} (1 - (1+alpha)/i), computed in f64 then
// cast to f32 — exactly mirrors _gl_coeffs (float64 cumprod -> float32 cast).
struct Coeffs {
    float c[TT + 1];
};
static constexpr Coeffs make_coeffs() {
    Coeffs r{};
    r.c[0] = 1.0f;
    double cur = 1.0;
    for (int j = 1; j <= TT; ++j) {
        cur *= (1.0 - 1.5 / (double)j);  // (1+alpha) = 1.5
        r.c[j] = (float)cur;
    }
    return r;
}
static constexpr Coeffs CO = make_coeffs();

// One thread per (b,d) sequence — register-TILED triangular convolution.
//
// R1-R6 post-mortem: the monolithic inner loop gives every y[i] and every
// coefficient a 127-step live range with one use per step; under pressure the
// allocator parks y[] in AGPRs (v_accvgpr_read per use) or remats the literal
// (v_mov per FMA) -> invariant 19K VALU instrs/wave (~2 per FMA) across six
// rounds regardless of budget knobs. Fix is locality, not budgets:
// 16x16 tiling. Per step-block K (steps 16K+1..16K+16):
//   - full tiles I<K: copy y-tile into 16 VGPR temps ONCE (asm-pinned so the
//     copy can't be folded back into per-FMA AGPR reads), then 256 FMAs
//     reusing them; each tile uses a 31-coefficient band, each ~16x reused.
//   - diagonal tile: the sequential spike/reset part.
// Bit-exactness: for every k the chain still visits slots i=0..k-2 in
// ascending order with the same fmaf ops -> identical rounding to the
// passing R1 kernel (tiles ascend, s ascends within a tile; different k's
// use independent accumulators so interleaving them changes nothing).
__global__ __launch_bounds__(256) void gl_if_kernel(const float* __restrict__ x,
                                                    float* __restrict__ sp) {
    const int g = blockIdx.x * 256 + threadIdx.x;  // (b,d) flat index
    float y[TT];  // persistent reset-membrane history (AGPR residency is fine)

#pragma unroll
    for (int K = 0; K < TT / 16; ++K) {
        // x values for this step block: 16 independent loads, issued up front
        float xv[16];
#pragma unroll
        for (int r = 0; r < 16; ++r) {
            xv[r] = x[g + (size_t)(16 * K + r) * BD];
        }

        float acc[16];
#pragma unroll
        for (int r = 0; r < 16; ++r) acc[r] = 0.0f;

        // Full history tiles: slots 16I..16I+15 all satisfy i <= k-2 for
        // every k in this block (16I+15 <= 16K-1 < k-1).
#pragma unroll
        for (int I = 0; I < K; ++I) {
            float yt[16];
#pragma unroll
            for (int s = 0; s < 16; ++s) {
                yt[s] = y[16 * I + s];
                asm("" : "+v"(yt[s]));  // pin in VGPR; block copy-propagation
            }
#pragma unroll
            for (int r = 0; r < 16; ++r) {
#pragma unroll
                for (int s = 0; s < 16; ++s) {
                    // step k = 16K+r+1, slot i = 16I+s, coeff j = k-1-i
                    acc[r] = fmaf(CO.c[16 * (K - I) + r - s], yt[s], acc[r]);
                }
            }
        }

        // Diagonal tile + spike/reset (sequential part)
        float yn[16];
#pragma unroll
        for (int r = 0; r < 16; ++r) {
            float a = acc[r];
            // slots i = 16K+s with s <= r-1 (i <= k-2), ascending
#pragma unroll
            for (int s = 0; s < 16; ++s) {
                if (s <= r - 1) a = fmaf(CO.c[r - s], yn[s], a);
            }
            const float men0 = xv[r] - a;
            const float spike = (men0 > 1.0f) ? 1.0f : 0.0f;
            yn[r] = men0 - spike;  // VTH = 1.0
            sp[g + (size_t)(16 * K + r) * BD] = spike;
        }
#pragma unroll
        for (int r = 0; r < 16; ++r) y[16 * K + r] = yn[r];
    }
}

// Lorentz expmap: per row b, vv = -v0^2 + sum_{d>=1} vd^2; s = sqrt(max(vv,eps));
// out = cosh(s)*z + (sinh(s)/s)*v.  One block per row, one thread per d.
__global__ __launch_bounds__(256) void expmap_kernel(const float* __restrict__ v,
                                                     const float* __restrict__ z,
                                                     float* __restrict__ out) {
    const int b = blockIdx.x;
    const int d = threadIdx.x;
    const size_t idx = (size_t)b * DDIM + d;
    const float vd = v[idx];

    float term = vd * vd;
    if (d == 0) term = -term;

    // reduce across the 256-thread block (4 waves of 64)
    float sum = term;
#pragma unroll
    for (int off = 32; off > 0; off >>= 1) sum += __shfl_down(sum, off, 64);

    __shared__ float ws[4];
    if ((threadIdx.x & 63) == 0) ws[threadIdx.x >> 6] = sum;
    __syncthreads();
    const float vv = ws[0] + ws[1] + ws[2] + ws[3];

    const float s2 = fmaxf(vv, 1e-6f);
    const float s = sqrtf(s2);
    const float ch = coshf(s);
    const float shs = sinhf(s) / s;

    out[idx] = ch * z[idx] + shs * vd;
}

extern "C" void kernel_launch(void* const* d_in, const int* in_sizes, int n_in,
                              void* d_out, int out_size, void* d_ws, size_t ws_size,
                              hipStream_t stream) {
    const float* x_seq = (const float*)d_in[0];
    const float* v_seq = (const float*)d_in[1];
    const float* z_seq = (const float*)d_in[2];

    float* s_out = (float*)d_out;                       // [T,B,D] spikes
    float* z_out = (float*)d_out + (size_t)TT * BD;     // [B,D] expmap

    gl_if_kernel<<<BD / 256, 256, 0, stream>>>(x_seq, s_out);
    expmap_kernel<<<BB, DDIM, 0, stream>>>(v_seq, z_seq, z_out);
}